// Round 16
// baseline (563.061 us; speedup 1.0000x reference)
//
#include <hip/hip_runtime.h>
#include <stdint.h>

typedef unsigned short u16;
typedef __bf16 bf16x8 __attribute__((ext_vector_type(8)));
typedef float f32x4 __attribute__((ext_vector_type(4)));

__device__ __forceinline__ u16 f2b(float x) {
  uint32_t b = __float_as_uint(x);
  b += 0x7fff + ((b >> 16) & 1);
  return (u16)(b >> 16);
}
__device__ __forceinline__ float b2f(u16 u) {
  return __uint_as_float(((uint32_t)u) << 16);
}

#define GLD16(src, dst)                                                                  \
  __builtin_amdgcn_global_load_lds((const __attribute__((address_space(1))) void*)(src),\
                                   (__attribute__((address_space(3))) void*)(dst), 16, 0, 0)

__device__ __forceinline__ f32x4 mfma16(bf16x8 a, bf16x8 b, f32x4 c) {
  return __builtin_amdgcn_mfma_f32_16x16x32_bf16(a, b, c, 0, 0, 0);
}

// ---------------- RoPE cos/sin table
__global__ void k_rope_table(float2* __restrict__ tab) {
  int i = blockIdx.x * 256 + threadIdx.x;  // 65536 = 1024 * 64
  int l = i >> 6, d = i & 63;
  float inv = powf(10000.0f, -(float)(2 * d) / 128.0f);
  float ang = (float)l * inv;
  float s, c;
  sincosf(ang, &s, &c);
  tab[i] = make_float2(c, s);
}

// ---------------- fp32 -> bf16 cast, 8 elems/thread
__global__ void k_cast8(const float* __restrict__ src, u16* __restrict__ dst) {
  size_t i = (size_t)blockIdx.x * 256 + threadIdx.x;
  const float4* s4 = (const float4*)src;
  float4 a = s4[2 * i], b = s4[2 * i + 1];
  union { u16 u[8]; uint4 v; } o;
  o.u[0] = f2b(a.x); o.u[1] = f2b(a.y); o.u[2] = f2b(a.z); o.u[3] = f2b(a.w);
  o.u[4] = f2b(b.x); o.u[5] = f2b(b.y); o.u[6] = f2b(b.z); o.u[7] = f2b(b.w);
  ((uint4*)dst)[i] = o.v;
}

// ---------------- transpose-cast: src fp32 [R][C] -> dst bf16 [C][R]
__global__ __launch_bounds__(256) void k_tcast(const float* __restrict__ src,
                                               u16* __restrict__ dst, int R, int C) {
  __shared__ u16 t[64][72];
  int tiles_c = C >> 6;
  int tr = blockIdx.x / tiles_c, tc = blockIdx.x % tiles_c;
  int tid = threadIdx.x;
  {
    int rr = tid >> 4, cv = tid & 15;
#pragma unroll
    for (int it = 0; it < 4; ++it) {
      int row = rr + it * 16;
      float4 v = *(const float4*)(src + (size_t)(tr * 64 + row) * C + tc * 64 + cv * 4);
      t[row][cv * 4 + 0] = f2b(v.x);
      t[row][cv * 4 + 1] = f2b(v.y);
      t[row][cv * 4 + 2] = f2b(v.z);
      t[row][cv * 4 + 3] = f2b(v.w);
    }
  }
  __syncthreads();
  {
    int cc = tid >> 3, g = tid & 7;
#pragma unroll
    for (int it = 0; it < 2; ++it) {
      int c = cc + it * 32;
      union { u16 u[8]; uint4 v; } o;
#pragma unroll
      for (int j = 0; j < 8; ++j) o.u[j] = t[g * 8 + j][c];
      *(uint4*)(dst + (size_t)(tc * 64 + c) * R + tr * 64 + g * 8) = o.v;
    }
  }
}

// ---------------- V transpose
__global__ __launch_bounds__(256) void k_vtrans(const u16* __restrict__ qkv,
                                                u16* __restrict__ vrt) {
  __shared__ u16 t[64][72];
  int b = blockIdx.x >> 8;
  int tt = blockIdx.x & 255;
  int tr = tt >> 4, tc = tt & 15;
  int tid = threadIdx.x;
  {
    int rr = tid >> 3, g = tid & 7;
#pragma unroll
    for (int it = 0; it < 2; ++it) {
      int row = rr + it * 32;
      union { u16 u[8]; uint4 v; } o;
      o.v = *(const uint4*)(qkv + (size_t)(b * 1024 + tr * 64 + row) * 6144 + 5120 + tc * 64 + g * 8);
#pragma unroll
      for (int j = 0; j < 8; ++j) t[row][g * 8 + j] = o.u[j];
    }
  }
  __syncthreads();
  {
    int cc = tid >> 3, g = tid & 7;
#pragma unroll
    for (int it = 0; it < 2; ++it) {
      int c = cc + it * 32;
      union { u16 u[8]; uint4 v; } o;
#pragma unroll
      for (int j = 0; j < 8; ++j) o.u[j] = t[g * 8 + j][c];
      *(uint4*)(vrt + (size_t)(b * 1024 + tc * 64 + c) * 1024 + tr * 64 + g * 8) = o.v;
    }
  }
}

// ---------------- RoPE scatter, vectorized 8 pairs/thread (G13)
// q gets scale/sqrt(D) * log2(e) folded in (attention uses exp2 -- see k_attn).
__global__ __launch_bounds__(320) void k_rope8(const u16* __restrict__ qkv,
                                               const float2* __restrict__ tab,
                                               u16* __restrict__ qr, u16* __restrict__ kr) {
  int row = blockIdx.x;                 // 4096 rows (b*1024+l)
  int j = threadIdx.x * 8;              // pair index: 0..2047 q, 2048..2559 k
  int b = row >> 10, l = row & 1023;
  const float qs = 0.12751586584003446f;  // 128^-0.5 * log2(e)
  bool isq = (j < 2048);
  int jj = isq ? j : (j - 2048);
  int h = jj >> 6, dp = jj & 63;
  const u16* src = qkv + (size_t)row * 6144 + (isq ? 0 : 4096) + h * 128 + 2 * dp;
  uint4 v0 = *(const uint4*)(src);
  uint4 v1 = *(const uint4*)(src + 8);
  const float2* tb = tab + l * 64 + dp;
  float sc = isq ? qs : 1.0f;
  union { u16 u[16]; uint4 v[2]; } o;
  const uint32_t* w = (const uint32_t*)&v0;
#pragma unroll
  for (int i = 0; i < 8; ++i) {
    uint32_t pair = (i < 4) ? w[i] : ((const uint32_t*)&v1)[i - 4];
    float2 cs = tb[i];
    float x1 = b2f((u16)pair), x2 = b2f((u16)(pair >> 16));
    float r1 = (x1 * cs.x - x2 * cs.y) * sc;
    float r2 = (x1 * cs.y + x2 * cs.x) * sc;
    o.u[2 * i] = f2b(r1);
    o.u[2 * i + 1] = f2b(r2);
  }
  u16* dst = isq ? (qr + ((size_t)((b * 32 + h) * 1024 + l)) * 128 + 2 * dp)
                 : (kr + ((size_t)((b * 8 + h) * 1024 + l)) * 128 + 2 * dp);
  *(uint4*)(dst) = o.v[0];
  *(uint4*)(dst + 8) = o.v[1];
}

// ================= 256x256 8-phase bf16 GEMM (R15 verbatim) =================
#define STAGE2(s0, s1, koff, ldsoff)          \
  GLD16((s0) + (koff), dst0 + (ldsoff));      \
  GLD16((s1) + (koff), dst1 + (ldsoff));

#define LOADB(base, kh)                                                   \
  bfr[0] = *(const bf16x8*)((base) + (kh) * 8192 + 0 * 512);              \
  bfr[1] = *(const bf16x8*)((base) + (kh) * 8192 + 1 * 512);              \
  bfr[2] = *(const bf16x8*)((base) + (kh) * 8192 + 2 * 512);              \
  bfr[3] = *(const bf16x8*)((base) + (kh) * 8192 + 3 * 512);

#define LOADA(base, kh, mh)                                               \
  afr[0] = *(const bf16x8*)((base) + (kh) * 8192 + (mh) * 2048 + 0 * 512);\
  afr[1] = *(const bf16x8*)((base) + (kh) * 8192 + (mh) * 2048 + 1 * 512);\
  afr[2] = *(const bf16x8*)((base) + (kh) * 8192 + (mh) * 2048 + 2 * 512);\
  afr[3] = *(const bf16x8*)((base) + (kh) * 8192 + (mh) * 2048 + 3 * 512);

#define PH(mh)                                                            \
  __builtin_amdgcn_s_barrier();                                           \
  asm volatile("s_waitcnt lgkmcnt(0)" ::: "memory");                      \
  __builtin_amdgcn_s_setprio(1);                                          \
  _Pragma("unroll") for (int mm = 0; mm < 4; ++mm)                        \
    _Pragma("unroll") for (int n_ = 0; n_ < 4; ++n_)                      \
      acc[(mh) * 4 + mm][n_] = mfma16(afr[mm], bfr[n_], acc[(mh) * 4 + mm][n_]); \
  __builtin_amdgcn_s_setprio(0);                                          \
  __builtin_amdgcn_s_barrier();

#define PHV(mh, n)                                                        \
  __builtin_amdgcn_s_barrier();                                           \
  asm volatile("s_waitcnt lgkmcnt(0)" ::: "memory");                      \
  __builtin_amdgcn_s_setprio(1);                                          \
  _Pragma("unroll") for (int mm = 0; mm < 4; ++mm)                        \
    _Pragma("unroll") for (int n_ = 0; n_ < 4; ++n_)                      \
      acc[(mh) * 4 + mm][n_] = mfma16(afr[mm], bfr[n_], acc[(mh) * 4 + mm][n_]); \
  __builtin_amdgcn_s_setprio(0);                                          \
  asm volatile("s_waitcnt vmcnt(" #n ")" ::: "memory");                   \
  __builtin_amdgcn_s_barrier();

#define VMC(n) asm volatile("s_waitcnt vmcnt(" #n ")" ::: "memory");

template <typename OutT>
__global__ __launch_bounds__(512, 2) void k_gemm8(const u16* __restrict__ A,
                                                  const u16* __restrict__ Bt,
                                                  OutT* __restrict__ C,
                                                  int M, int N, int K) {
  extern __shared__ u16 lds[];
  const int tid = threadIdx.x;
  const int lane = tid & 63, wid = tid >> 6;
  const int l16 = lane & 15, lhi = lane >> 4;
  const int wm = wid >> 2, wn = wid & 3;

  const int nbn = N >> 8;
  int bid = blockIdx.x;
  const int cpx = gridDim.x >> 3;
  bid = (bid & 7) * cpx + (bid >> 3);  // XCD swizzle (grid % 8 == 0)
  const int bm = (bid / nbn) << 8;
  const int bn = (bid % nbn) << 8;

  const u16* Ag = A + (size_t)bm * K;
  const u16* Bg = Bt + (size_t)bn * K;

  const int swz = (lhi ^ ((l16 >> 1) & 3)) << 3;
  const u16* pA0 = lds + wm * 4096 + l16 * 32 + swz;
  const u16* pA1 = pA0 + 32768;
  const u16* pB0 = lds + 16384 + wn * 2048 + l16 * 32 + swz;
  const u16* pB1 = pB0 + 32768;

  const int r0 = tid >> 2, g0 = tid & 3;
  const int r1 = r0 + 128;
  const size_t so0 = (size_t)r0 * K + ((g0 ^ ((r0 >> 1) & 3)) << 3);
  const size_t so1 = (size_t)r1 * K + ((g0 ^ ((r1 >> 1) & 3)) << 3);
  const u16* sA0 = Ag + so0;
  const u16* sA1 = Ag + so1;
  const u16* sB0 = Bg + so0;
  const u16* sB1 = Bg + so1;
  u16* dst0 = lds + wid * 512;
  u16* dst1 = lds + 4096 + wid * 512;

  f32x4 acc[8][4] = {};
  bf16x8 bfr[4], afr[4];

  STAGE2(sA0, sA1, 0, 0);
  STAGE2(sA0, sA1, 32, 8192);
  STAGE2(sB0, sB1, 0, 16384);
  STAGE2(sB0, sB1, 32, 24576);
  STAGE2(sB0, sB1, 64, 49152);
  STAGE2(sA0, sA1, 64, 32768);
  STAGE2(sB0, sB1, 96, 57344);
  VMC(6)
  __builtin_amdgcn_s_barrier();

  const int nt = K >> 6;
  for (int t = 0; t < nt - 2; t += 2) {
    const int kA1 = (t + 1) * 64 + 32;
    const int k2 = (t + 2) * 64;
    const int k3 = (t + 3) * 64;
    LOADB(pB0, 0)
    LOADA(pA0, 0, 0)
    STAGE2(sA0, sA1, kA1, 40960);
    PH(0)
    LOADA(pA0, 0, 1)
    STAGE2(sB0, sB1, k2, 16384);
    PH(1)
    LOADB(pB0, 1)
    LOADA(pA0, 1, 0)
    STAGE2(sA0, sA1, k2, 0);
    PH(0)
    LOADA(pA0, 1, 1)
    STAGE2(sB0, sB1, k2 + 32, 24576);
    PHV(1, 6)
    LOADB(pB1, 0)
    LOADA(pA1, 0, 0)
    STAGE2(sA0, sA1, k2 + 32, 8192);
    PH(0)
    LOADA(pA1, 0, 1)
    STAGE2(sB0, sB1, k3, 49152);
    PH(1)
    LOADB(pB1, 1)
    LOADA(pA1, 1, 0)
    STAGE2(sA0, sA1, k3, 32768);
    PH(0)
    LOADA(pA1, 1, 1)
    STAGE2(sB0, sB1, k3 + 32, 57344);
    PHV(1, 6)
  }
  {
    const int kA1 = (nt - 1) * 64 + 32;
    LOADB(pB0, 0)
    LOADA(pA0, 0, 0)
    STAGE2(sA0, sA1, kA1, 40960);
    PH(0)
    LOADA(pA0, 0, 1)
    PH(1)
    LOADB(pB0, 1)
    LOADA(pA0, 1, 0)
    PH(0)
    LOADA(pA0, 1, 1)
    PHV(1, 0)
    LOADB(pB1, 0)
    LOADA(pA1, 0, 0)
    PH(0)
    LOADA(pA1, 0, 1)
    PH(1)
    LOADB(pB1, 1)
    LOADA(pA1, 1, 0)
    PH(0)
    LOADA(pA1, 1, 1)
    PH(1)
  }

#pragma unroll
  for (int m = 0; m < 8; ++m) {
    int row = bm + wm * 128 + m * 16 + lhi * 4;
#pragma unroll
    for (int n = 0; n < 4; ++n) {
      int col = bn + wn * 64 + n * 16 + l16;
#pragma unroll
      for (int r = 0; r < 4; ++r) {
        float v = acc[m][n][r];
        size_t idx = (size_t)(row + r) * N + col;
        if constexpr (sizeof(OutT) == 2) C[idx] = f2b(v);
        else C[idx] = v;
      }
    }
  }
}

// ---------------- flash attention: T14 async-STAGE (reg-staged K/V, issue-early
// write-late). R15 -> R16 single change: per kb, K/V for kb+1 are loaded to
// REGISTERS at the top (4 global_load_dwordx4/thread, +16 VGPR), the whole
// iteration computes from LDS, then: s_barrier (all waves' reads retired --
// in-order exec: each wave's pre-barrier MFMAs already waited on its ds_reads)
// -> ds_write regs to the SAME swizzled LDS slots -> lgkmcnt(0) -> s_barrier.
// No __syncthreads in the loop => no per-iteration vmcnt(0) drain; HBM latency
// hides under a full iteration (m214v27: +17%). LDS layout/size unchanged.
__global__ __launch_bounds__(512) void k_attn(const u16* __restrict__ qr,
                                              const u16* __restrict__ kr,
                                              const u16* __restrict__ vrt,
                                              u16* __restrict__ ao) {
  __shared__ u16 Klds[8192];   // [64 kv][128 d], xor-swizzled granules
  __shared__ u16 Vlds[8192];   // [128 d][64 kv], xor-swizzled granules
  __shared__ u16 Plds[9216];   // 8 waves * [16][72]
  int bid = blockIdx.x;
  int qb = bid & 7, h = (bid >> 3) & 31, b = bid >> 8;
  int kvh = h & 7;
  int lane = threadIdx.x & 63, w = threadIdx.x >> 6;
  int l16 = lane & 15, lhi = lane >> 4;
  int qmin = qb * 128 + w * 16;

  const u16* qbase = qr + ((size_t)((b * 32 + h) * 1024) + qmin + l16) * 128;
  bf16x8 aq[4];
#pragma unroll
  for (int kc = 0; kc < 4; ++kc) aq[kc] = *(const bf16x8*)(qbase + kc * 32 + lhi * 8);

  const u16* Kg = kr + (size_t)(b * 8 + kvh) * (1024 * 128);
  const u16* Vg = vrt + (size_t)(b * 8 + kvh) * (128 * 1024);

  // chunk mapping (identical addresses to the old GLD16 staging)
  const int c0 = w * 128 + lane;
  const int c1 = c0 + 64;
  const int kr0 = c0 >> 4, kg0 = c0 & 15;
  const int kr1 = c1 >> 4, kg1 = c1 & 15;
  const int ks0 = (kg0 ^ (kr0 & 7)) * 8;
  const int ks1 = (kg1 ^ (kr1 & 7)) * 8;
  const int vd0 = c0 >> 3, vg0 = c0 & 7;
  const int vd1 = c1 >> 3, vg1 = c1 & 7;
  const int vs0 = (vg0 ^ (vd0 & 7)) * 8;
  const int vs1 = (vg1 ^ (vd1 & 7)) * 8;

  uint4 kreg0, kreg1, vreg0, vreg1;
#define LOADKV(kv0_)                                                          \
  kreg0 = *(const uint4*)(Kg + (size_t)((kv0_) + kr0) * 128 + ks0);           \
  kreg1 = *(const uint4*)(Kg + (size_t)((kv0_) + kr1) * 128 + ks1);           \
  vreg0 = *(const uint4*)(Vg + (size_t)vd0 * 1024 + (kv0_) + vs0);            \
  vreg1 = *(const uint4*)(Vg + (size_t)vd1 * 1024 + (kv0_) + vs1);
#define WRITEKV()                                                             \
  *(uint4*)(Klds + c0 * 8) = kreg0;                                           \
  *(uint4*)(Klds + c1 * 8) = kreg1;                                           \
  *(uint4*)(Vlds + c0 * 8) = vreg0;                                           \
  *(uint4*)(Vlds + c1 * 8) = vreg1;

  float m_run[4] = {-1e30f, -1e30f, -1e30f, -1e30f};
  float l_part[4] = {0.f, 0.f, 0.f, 0.f};
  f32x4 o[8] = {};

  int nkb = 2 * qb + 2;
  // prologue: kb=0 tile via regs -> LDS
  LOADKV(0)
  WRITEKV()
  __syncthreads();

  for (int kb = 0; kb < nkb; ++kb) {
    int kv0 = kb * 64;
    const bool more = (kb + 1) < nkb;
    if (more) { LOADKV(kv0 + 64) }  // issue-early; consumed after the barrier

    f32x4 s[4] = {};
#pragma unroll
    for (int kc = 0; kc < 4; ++kc) {
#pragma unroll
      for (int n = 0; n < 4; ++n) {
        int kv = n * 16 + l16;
        int g = kc * 4 + lhi;
        bf16x8 bk = *(const bf16x8*)(Klds + kv * 128 + ((g ^ (kv & 7)) * 8));
        s[n] = mfma16(aq[kc], bk, s[n]);
      }
    }
    if (kv0 + 63 > qmin) {
#pragma unroll
      for (int n = 0; n < 4; ++n)
#pragma unroll
        for (int r = 0; r < 4; ++r) {
          int q = qmin + lhi * 4 + r;
          int kv = kv0 + n * 16 + l16;
          if (kv > q) s[n][r] = -1e30f;
        }
    }
    float mx[4];
    bool need = false;
#pragma unroll
    for (int r = 0; r < 4; ++r) {
      float m0 = fmaxf(fmaxf(s[0][r], s[1][r]), fmaxf(s[2][r], s[3][r]));
      m0 = fmaxf(m0, __shfl_xor(m0, 1));
      m0 = fmaxf(m0, __shfl_xor(m0, 2));
      m0 = fmaxf(m0, __shfl_xor(m0, 4));
      m0 = fmaxf(m0, __shfl_xor(m0, 8));
      mx[r] = m0;
      need = need || (m0 > m_run[r] + 11.0f);
    }
    if (__any(need)) {
#pragma unroll
      for (int r = 0; r < 4; ++r) {
        float mn = fmaxf(m_run[r], mx[r]);
        float sf = exp2f(m_run[r] - mn);
        m_run[r] = mn;
        l_part[r] *= sf;
#pragma unroll
        for (int nd = 0; nd < 8; ++nd) o[nd][r] *= sf;
      }
    }
    u16* pw = Plds + w * 1152;
#pragma unroll
    for (int r = 0; r < 4; ++r) {
      float lsum = 0.f;
#pragma unroll
      for (int n = 0; n < 4; ++n) {
        float p = exp2f(s[n][r] - m_run[r]);
        lsum += p;
        pw[(lhi * 4 + r) * 72 + n * 16 + l16] = f2b(p);
      }
      l_part[r] += lsum;
    }
#pragma unroll
    for (int kc = 0; kc < 2; ++kc) {
      bf16x8 ap = *(const bf16x8*)(pw + l16 * 72 + kc * 32 + lhi * 8);
#pragma unroll
      for (int nd = 0; nd < 8; ++nd) {
        int d = nd * 16 + l16;
        int g = kc * 4 + lhi;
        bf16x8 bv = *(const bf16x8*)(Vlds + d * 64 + ((g ^ (d & 7)) * 8));
        o[nd] = mfma16(ap, bv, o[nd]);
      }
    }
    // all this wave's LDS reads retired (their lgkm waits preceded the MFMAs)
    __builtin_amdgcn_s_barrier();
    if (more) {
      WRITEKV()  // compiler inserts the vmcnt waits for kreg*/vreg* deps
      asm volatile("s_waitcnt lgkmcnt(0)" ::: "memory");
    }
    __builtin_amdgcn_s_barrier();
  }
#pragma unroll
  for (int r = 0; r < 4; ++r) {
    float l = l_part[r];
    l += __shfl_xor(l, 1);
    l += __shfl_xor(l, 2);
    l += __shfl_xor(l, 4);
    l += __shfl_xor(l, 8);
    float inv = 1.0f / l;
    int q = qmin + lhi * 4 + r;
    u16* orow = ao + ((size_t)(b * 1024 + q)) * 4096 + h * 128;
#pragma unroll
    for (int nd = 0; nd < 8; ++nd) orow[nd * 16 + l16] = f2b(o[nd][r] * inv);
  }
#undef LOADKV
#undef WRITEKV
}

extern "C" void kernel_launch(void* const* d_in, const int* in_sizes, int n_in,
                              void* d_out, int out_size, void* d_ws, size_t ws_size,
                              hipStream_t stream) {
  const float* x = (const float*)d_in[0];
  const float* wq = (const float*)d_in[2];
  const float* wk = (const float*)d_in[3];
  const float* wv = (const float*)d_in[4];
  const float* wo = (const float*)d_in[5];

  char* ws = (char*)d_ws;
  u16* xb = (u16*)(ws + 0);
  u16* wcat = (u16*)(ws + 33554432);
  u16* qr = (u16*)(ws + 0);
  u16* kr = (u16*)(ws + 33554432);
  u16* vrt = (u16*)(ws + 41943040);
  u16* ao = (u16*)(ws + 50331648);
  u16* wob = (u16*)(ws + 83886080);
  float2* tab = (float2*)(ws + 117440512);
  u16* qkv = (u16*)d_out;

  hipFuncSetAttribute((const void*)k_gemm8<u16>,
                      hipFuncAttributeMaxDynamicSharedMemorySize, 131072);
  hipFuncSetAttribute((const void*)k_gemm8<float>,
                      hipFuncAttributeMaxDynamicSharedMemorySize, 131072);

  k_rope_table<<<256, 256, 0, stream>>>(tab);
  k_cast8<<<8192, 256, 0, stream>>>(x, xb);
  k_tcast<<<4096, 256, 0, stream>>>(wq, wcat, 4096, 4096);
  k_tcast<<<1024, 256, 0, stream>>>(wk, wcat + (size_t)4096 * 4096, 4096, 1024);
  k_tcast<<<1024, 256, 0, stream>>>(wv, wcat + (size_t)5120 * 4096, 4096, 1024);
  k_tcast<<<4096, 256, 0, stream>>>(wo, wob, 4096, 4096);
  k_gemm8<u16><<<384, 512, 131072, stream>>>(xb, wcat, qkv, 4096, 6144, 4096);
  k_rope8<<<4096, 320, 0, stream>>>(qkv, tab, qr, kr);
  k_vtrans<<<1024, 256, 0, stream>>>(qkv, vrt);
  k_attn<<<1024, 512, 0, stream>>>(qr, kr, vrt, ao);
  k_gemm8<float><<<256, 512, 131072, stream>>>(ao, wob, (float*)d_out, 4096, 4096, 4096);
}

// Round 17
// 535.230 us; speedup vs baseline: 1.0520x; 1.0520x over previous
//
#include <hip/hip_runtime.h>
#include <stdint.h>

typedef unsigned short u16;
typedef __bf16 bf16x8 __attribute__((ext_vector_type(8)));
typedef float f32x4 __attribute__((ext_vector_type(4)));

__device__ __forceinline__ u16 f2b(float x) {
  uint32_t b = __float_as_uint(x);
  b += 0x7fff + ((b >> 16) & 1);
  return (u16)(b >> 16);
}
__device__ __forceinline__ float b2f(u16 u) {
  return __uint_as_float(((uint32_t)u) << 16);
}

#define GLD16(src, dst)                                                                  \
  __builtin_amdgcn_global_load_lds((const __attribute__((address_space(1))) void*)(src),\
                                   (__attribute__((address_space(3))) void*)(dst), 16, 0, 0)

__device__ __forceinline__ f32x4 mfma16(bf16x8 a, bf16x8 b, f32x4 c) {
  return __builtin_amdgcn_mfma_f32_16x16x32_bf16(a, b, c, 0, 0, 0);
}

// ---------------- RoPE cos/sin table
__global__ void k_rope_table(float2* __restrict__ tab) {
  int i = blockIdx.x * 256 + threadIdx.x;  // 65536 = 1024 * 64
  int l = i >> 6, d = i & 63;
  float inv = powf(10000.0f, -(float)(2 * d) / 128.0f);
  float ang = (float)l * inv;
  float s, c;
  sincosf(ang, &s, &c);
  tab[i] = make_float2(c, s);
}

// ---------------- fp32 -> bf16 cast, 8 elems/thread
__global__ void k_cast8(const float* __restrict__ src, u16* __restrict__ dst) {
  size_t i = (size_t)blockIdx.x * 256 + threadIdx.x;
  const float4* s4 = (const float4*)src;
  float4 a = s4[2 * i], b = s4[2 * i + 1];
  union { u16 u[8]; uint4 v; } o;
  o.u[0] = f2b(a.x); o.u[1] = f2b(a.y); o.u[2] = f2b(a.z); o.u[3] = f2b(a.w);
  o.u[4] = f2b(b.x); o.u[5] = f2b(b.y); o.u[6] = f2b(b.z); o.u[7] = f2b(b.w);
  ((uint4*)dst)[i] = o.v;
}

// ---------------- transpose-cast tile body: src fp32 [4096][C] tile -> dst bf16 [C][4096]
__device__ __forceinline__ void tcast_tile(const float* __restrict__ src,
                                           u16* __restrict__ dst, int C, int t) {
  __shared__ u16 tbuf[64][72];
  int tiles_c = C >> 6;
  int tr = t / tiles_c, tc = t % tiles_c;
  int tid = threadIdx.x;
  const int R = 4096;
  {
    int rr = tid >> 4, cv = tid & 15;
#pragma unroll
    for (int it = 0; it < 4; ++it) {
      int row = rr + it * 16;
      float4 v = *(const float4*)(src + (size_t)(tr * 64 + row) * C + tc * 64 + cv * 4);
      tbuf[row][cv * 4 + 0] = f2b(v.x);
      tbuf[row][cv * 4 + 1] = f2b(v.y);
      tbuf[row][cv * 4 + 2] = f2b(v.z);
      tbuf[row][cv * 4 + 3] = f2b(v.w);
    }
  }
  __syncthreads();
  {
    int cc = tid >> 3, g = tid & 7;
#pragma unroll
    for (int it = 0; it < 2; ++it) {
      int c = cc + it * 32;
      union { u16 u[8]; uint4 v; } o;
#pragma unroll
      for (int j = 0; j < 8; ++j) o.u[j] = tbuf[g * 8 + j][c];
      *(uint4*)(dst + (size_t)(tc * 64 + c) * R + tr * 64 + g * 8) = o.v;
    }
  }
}

// single-source transpose-cast (used for wo)
__global__ __launch_bounds__(256) void k_tcast(const float* __restrict__ src,
                                               u16* __restrict__ dst, int R, int C) {
  tcast_tile(src, dst, C, blockIdx.x);
}

// fused wq|wk|wv transpose-cast: blocks [0,4096) wq, [4096,5120) wk, [5120,6144) wv
__global__ __launch_bounds__(256) void k_tcast3(const float* __restrict__ wq,
                                                const float* __restrict__ wk,
                                                const float* __restrict__ wv,
                                                u16* __restrict__ wcat) {
  int bidx = blockIdx.x;
  if (bidx < 4096) {
    tcast_tile(wq, wcat, 4096, bidx);
  } else if (bidx < 5120) {
    tcast_tile(wk, wcat + (size_t)4096 * 4096, 1024, bidx - 4096);
  } else {
    tcast_tile(wv, wcat + (size_t)5120 * 4096, 1024, bidx - 5120);
  }
}

// ---------------- V transpose
__global__ __launch_bounds__(256) void k_vtrans(const u16* __restrict__ qkv,
                                                u16* __restrict__ vrt) {
  __shared__ u16 t[64][72];
  int b = blockIdx.x >> 8;
  int tt = blockIdx.x & 255;
  int tr = tt >> 4, tc = tt & 15;
  int tid = threadIdx.x;
  {
    int rr = tid >> 3, g = tid & 7;
#pragma unroll
    for (int it = 0; it < 2; ++it) {
      int row = rr + it * 32;
      union { u16 u[8]; uint4 v; } o;
      o.v = *(const uint4*)(qkv + (size_t)(b * 1024 + tr * 64 + row) * 6144 + 5120 + tc * 64 + g * 8);
#pragma unroll
      for (int j = 0; j < 8; ++j) t[row][g * 8 + j] = o.u[j];
    }
  }
  __syncthreads();
  {
    int cc = tid >> 3, g = tid & 7;
#pragma unroll
    for (int it = 0; it < 2; ++it) {
      int c = cc + it * 32;
      union { u16 u[8]; uint4 v; } o;
#pragma unroll
      for (int j = 0; j < 8; ++j) o.u[j] = t[g * 8 + j][c];
      *(uint4*)(vrt + (size_t)(b * 1024 + tc * 64 + c) * 1024 + tr * 64 + g * 8) = o.v;
    }
  }
}

// ---------------- RoPE scatter, vectorized 8 pairs/thread (G13)
__global__ __launch_bounds__(320) void k_rope8(const u16* __restrict__ qkv,
                                               const float2* __restrict__ tab,
                                               u16* __restrict__ qr, u16* __restrict__ kr) {
  int row = blockIdx.x;                 // 4096 rows (b*1024+l)
  int j = threadIdx.x * 8;              // pair index: 0..2047 q, 2048..2559 k
  int b = row >> 10, l = row & 1023;
  const float qs = 0.12751586584003446f;  // 128^-0.5 * log2(e)
  bool isq = (j < 2048);
  int jj = isq ? j : (j - 2048);
  int h = jj >> 6, dp = jj & 63;
  const u16* src = qkv + (size_t)row * 6144 + (isq ? 0 : 4096) + h * 128 + 2 * dp;
  uint4 v0 = *(const uint4*)(src);
  uint4 v1 = *(const uint4*)(src + 8);
  const float2* tb = tab + l * 64 + dp;
  float sc = isq ? qs : 1.0f;
  union { u16 u[16]; uint4 v[2]; } o;
  const uint32_t* w = (const uint32_t*)&v0;
#pragma unroll
  for (int i = 0; i < 8; ++i) {
    uint32_t pair = (i < 4) ? w[i] : ((const uint32_t*)&v1)[i - 4];
    float2 cs = tb[i];
    float x1 = b2f((u16)pair), x2 = b2f((u16)(pair >> 16));
    float r1 = (x1 * cs.x - x2 * cs.y) * sc;
    float r2 = (x1 * cs.y + x2 * cs.x) * sc;
    o.u[2 * i] = f2b(r1);
    o.u[2 * i + 1] = f2b(r2);
  }
  u16* dst = isq ? (qr + ((size_t)((b * 32 + h) * 1024 + l)) * 128 + 2 * dp)
                 : (kr + ((size_t)((b * 8 + h) * 1024 + l)) * 128 + 2 * dp);
  *(uint4*)(dst) = o.v[0];
  *(uint4*)(dst + 8) = o.v[1];
}

// ================= 256x256 8-phase bf16 GEMM (R15 verbatim) =================
#define STAGE2(s0, s1, koff, ldsoff)          \
  GLD16((s0) + (koff), dst0 + (ldsoff));      \
  GLD16((s1) + (koff), dst1 + (ldsoff));

#define LOADB(base, kh)                                                   \
  bfr[0] = *(const bf16x8*)((base) + (kh) * 8192 + 0 * 512);              \
  bfr[1] = *(const bf16x8*)((base) + (kh) * 8192 + 1 * 512);              \
  bfr[2] = *(const bf16x8*)((base) + (kh) * 8192 + 2 * 512);              \
  bfr[3] = *(const bf16x8*)((base) + (kh) * 8192 + 3 * 512);

#define LOADA(base, kh, mh)                                               \
  afr[0] = *(const bf16x8*)((base) + (kh) * 8192 + (mh) * 2048 + 0 * 512);\
  afr[1] = *(const bf16x8*)((base) + (kh) * 8192 + (mh) * 2048 + 1 * 512);\
  afr[2] = *(const bf16x8*)((base) + (kh) * 8192 + (mh) * 2048 + 2 * 512);\
  afr[3] = *(const bf16x8*)((base) + (kh) * 8192 + (mh) * 2048 + 3 * 512);

#define PH(mh)                                                            \
  __builtin_amdgcn_s_barrier();                                           \
  asm volatile("s_waitcnt lgkmcnt(0)" ::: "memory");                      \
  __builtin_amdgcn_s_setprio(1);                                          \
  _Pragma("unroll") for (int mm = 0; mm < 4; ++mm)                        \
    _Pragma("unroll") for (int n_ = 0; n_ < 4; ++n_)                      \
      acc[(mh) * 4 + mm][n_] = mfma16(afr[mm], bfr[n_], acc[(mh) * 4 + mm][n_]); \
  __builtin_amdgcn_s_setprio(0);                                          \
  __builtin_amdgcn_s_barrier();

#define PHV(mh, n)                                                        \
  __builtin_amdgcn_s_barrier();                                           \
  asm volatile("s_waitcnt lgkmcnt(0)" ::: "memory");                      \
  __builtin_amdgcn_s_setprio(1);                                          \
  _Pragma("unroll") for (int mm = 0; mm < 4; ++mm)                        \
    _Pragma("unroll") for (int n_ = 0; n_ < 4; ++n_)                      \
      acc[(mh) * 4 + mm][n_] = mfma16(afr[mm], bfr[n_], acc[(mh) * 4 + mm][n_]); \
  __builtin_amdgcn_s_setprio(0);                                          \
  asm volatile("s_waitcnt vmcnt(" #n ")" ::: "memory");                   \
  __builtin_amdgcn_s_barrier();

#define VMC(n) asm volatile("s_waitcnt vmcnt(" #n ")" ::: "memory");

template <typename OutT>
__global__ __launch_bounds__(512, 2) void k_gemm8(const u16* __restrict__ A,
                                                  const u16* __restrict__ Bt,
                                                  OutT* __restrict__ C,
                                                  int M, int N, int K) {
  extern __shared__ u16 lds[];
  const int tid = threadIdx.x;
  const int lane = tid & 63, wid = tid >> 6;
  const int l16 = lane & 15, lhi = lane >> 4;
  const int wm = wid >> 2, wn = wid & 3;

  const int nbn = N >> 8;
  int bid = blockIdx.x;
  const int cpx = gridDim.x >> 3;
  bid = (bid & 7) * cpx + (bid >> 3);  // XCD swizzle (grid % 8 == 0)
  const int bm = (bid / nbn) << 8;
  const int bn = (bid % nbn) << 8;

  const u16* Ag = A + (size_t)bm * K;
  const u16* Bg = Bt + (size_t)bn * K;

  const int swz = (lhi ^ ((l16 >> 1) & 3)) << 3;
  const u16* pA0 = lds + wm * 4096 + l16 * 32 + swz;
  const u16* pA1 = pA0 + 32768;
  const u16* pB0 = lds + 16384 + wn * 2048 + l16 * 32 + swz;
  const u16* pB1 = pB0 + 32768;

  const int r0 = tid >> 2, g0 = tid & 3;
  const int r1 = r0 + 128;
  const size_t so0 = (size_t)r0 * K + ((g0 ^ ((r0 >> 1) & 3)) << 3);
  const size_t so1 = (size_t)r1 * K + ((g0 ^ ((r1 >> 1) & 3)) << 3);
  const u16* sA0 = Ag + so0;
  const u16* sA1 = Ag + so1;
  const u16* sB0 = Bg + so0;
  const u16* sB1 = Bg + so1;
  u16* dst0 = lds + wid * 512;
  u16* dst1 = lds + 4096 + wid * 512;

  f32x4 acc[8][4] = {};
  bf16x8 bfr[4], afr[4];

  STAGE2(sA0, sA1, 0, 0);
  STAGE2(sA0, sA1, 32, 8192);
  STAGE2(sB0, sB1, 0, 16384);
  STAGE2(sB0, sB1, 32, 24576);
  STAGE2(sB0, sB1, 64, 49152);
  STAGE2(sA0, sA1, 64, 32768);
  STAGE2(sB0, sB1, 96, 57344);
  VMC(6)
  __builtin_amdgcn_s_barrier();

  const int nt = K >> 6;
  for (int t = 0; t < nt - 2; t += 2) {
    const int kA1 = (t + 1) * 64 + 32;
    const int k2 = (t + 2) * 64;
    const int k3 = (t + 3) * 64;
    LOADB(pB0, 0)
    LOADA(pA0, 0, 0)
    STAGE2(sA0, sA1, kA1, 40960);
    PH(0)
    LOADA(pA0, 0, 1)
    STAGE2(sB0, sB1, k2, 16384);
    PH(1)
    LOADB(pB0, 1)
    LOADA(pA0, 1, 0)
    STAGE2(sA0, sA1, k2, 0);
    PH(0)
    LOADA(pA0, 1, 1)
    STAGE2(sB0, sB1, k2 + 32, 24576);
    PHV(1, 6)
    LOADB(pB1, 0)
    LOADA(pA1, 0, 0)
    STAGE2(sA0, sA1, k2 + 32, 8192);
    PH(0)
    LOADA(pA1, 0, 1)
    STAGE2(sB0, sB1, k3, 49152);
    PH(1)
    LOADB(pB1, 1)
    LOADA(pA1, 1, 0)
    STAGE2(sA0, sA1, k3, 32768);
    PH(0)
    LOADA(pA1, 1, 1)
    STAGE2(sB0, sB1, k3 + 32, 57344);
    PHV(1, 6)
  }
  {
    const int kA1 = (nt - 1) * 64 + 32;
    LOADB(pB0, 0)
    LOADA(pA0, 0, 0)
    STAGE2(sA0, sA1, kA1, 40960);
    PH(0)
    LOADA(pA0, 0, 1)
    PH(1)
    LOADB(pB0, 1)
    LOADA(pA0, 1, 0)
    PH(0)
    LOADA(pA0, 1, 1)
    PHV(1, 0)
    LOADB(pB1, 0)
    LOADA(pA1, 0, 0)
    PH(0)
    LOADA(pA1, 0, 1)
    PH(1)
    LOADB(pB1, 1)
    LOADA(pA1, 1, 0)
    PH(0)
    LOADA(pA1, 1, 1)
    PH(1)
  }

#pragma unroll
  for (int m = 0; m < 8; ++m) {
    int row = bm + wm * 128 + m * 16 + lhi * 4;
#pragma unroll
    for (int n = 0; n < 4; ++n) {
      int col = bn + wn * 64 + n * 16 + l16;
#pragma unroll
      for (int r = 0; r < 4; ++r) {
        float v = acc[m][n][r];
        size_t idx = (size_t)(row + r) * N + col;
        if constexpr (sizeof(OutT) == 2) C[idx] = f2b(v);
        else C[idx] = v;
      }
    }
  }
}

// ---------------- flash attention (R12-exact: GLD16 staging, __syncthreads,
// P stride 72, defer-max + exp2 + deferred-l; part of the proven 539.6us run)
__global__ __launch_bounds__(512) void k_attn(const u16* __restrict__ qr,
                                              const u16* __restrict__ kr,
                                              const u16* __restrict__ vrt,
                                              u16* __restrict__ ao) {
  __shared__ u16 Klds[8192];
  __shared__ u16 Vlds[8192];
  __shared__ u16 Plds[9216];
  int bid = blockIdx.x;
  int qb = bid & 7, h = (bid >> 3) & 31, b = bid >> 8;
  int kvh = h & 7;
  int lane = threadIdx.x & 63, w = threadIdx.x >> 6;
  int l16 = lane & 15, lhi = lane >> 4;
  int qmin = qb * 128 + w * 16;

  const u16* qbase = qr + ((size_t)((b * 32 + h) * 1024) + qmin + l16) * 128;
  bf16x8 aq[4];
#pragma unroll
  for (int kc = 0; kc < 4; ++kc) aq[kc] = *(const bf16x8*)(qbase + kc * 32 + lhi * 8);

  const u16* Kg = kr + (size_t)(b * 8 + kvh) * (1024 * 128);
  const u16* Vg = vrt + (size_t)(b * 8 + kvh) * (128 * 1024);

  float m_run[4] = {-1e30f, -1e30f, -1e30f, -1e30f};
  float l_part[4] = {0.f, 0.f, 0.f, 0.f};
  f32x4 o[8] = {};

  int nkb = 2 * qb + 2;
  for (int kb = 0; kb < nkb; ++kb) {
    int kv0 = kb * 64;
#pragma unroll
    for (int i = 0; i < 2; ++i) {
      int c = w * 128 + i * 64 + lane;
      int krow = c >> 4, g = c & 15;
      GLD16(Kg + (size_t)(kv0 + krow) * 128 + ((g ^ (krow & 7)) * 8),
            Klds + (w * 128 + i * 64) * 8);
    }
#pragma unroll
    for (int i = 0; i < 2; ++i) {
      int c = w * 128 + i * 64 + lane;
      int d = c >> 3, g = c & 7;
      GLD16(Vg + (size_t)d * 1024 + kv0 + ((g ^ (d & 7)) * 8),
            Vlds + (w * 128 + i * 64) * 8);
    }
    __syncthreads();

    f32x4 s[4] = {};
#pragma unroll
    for (int kc = 0; kc < 4; ++kc) {
#pragma unroll
      for (int n = 0; n < 4; ++n) {
        int kv = n * 16 + l16;
        int g = kc * 4 + lhi;
        bf16x8 bk = *(const bf16x8*)(Klds + kv * 128 + ((g ^ (kv & 7)) * 8));
        s[n] = mfma16(aq[kc], bk, s[n]);
      }
    }
    if (kv0 + 63 > qmin) {
#pragma unroll
      for (int n = 0; n < 4; ++n)
#pragma unroll
        for (int r = 0; r < 4; ++r) {
          int q = qmin + lhi * 4 + r;
          int kv = kv0 + n * 16 + l16;
          if (kv > q) s[n][r] = -1e30f;
        }
    }
    float mx[4];
    bool need = false;
#pragma unroll
    for (int r = 0; r < 4; ++r) {
      float m0 = fmaxf(fmaxf(s[0][r], s[1][r]), fmaxf(s[2][r], s[3][r]));
      m0 = fmaxf(m0, __shfl_xor(m0, 1));
      m0 = fmaxf(m0, __shfl_xor(m0, 2));
      m0 = fmaxf(m0, __shfl_xor(m0, 4));
      m0 = fmaxf(m0, __shfl_xor(m0, 8));
      mx[r] = m0;
      need = need || (m0 > m_run[r] + 11.0f);
    }
    if (__any(need)) {
#pragma unroll
      for (int r = 0; r < 4; ++r) {
        float mn = fmaxf(m_run[r], mx[r]);
        float sf = exp2f(m_run[r] - mn);
        m_run[r] = mn;
        l_part[r] *= sf;
#pragma unroll
        for (int nd = 0; nd < 8; ++nd) o[nd][r] *= sf;
      }
    }
    u16* pw = Plds + w * 1152;
#pragma unroll
    for (int r = 0; r < 4; ++r) {
      float lsum = 0.f;
#pragma unroll
      for (int n = 0; n < 4; ++n) {
        float p = exp2f(s[n][r] - m_run[r]);
        lsum += p;
        pw[(lhi * 4 + r) * 72 + n * 16 + l16] = f2b(p);
      }
      l_part[r] += lsum;
    }
#pragma unroll
    for (int kc = 0; kc < 2; ++kc) {
      bf16x8 ap = *(const bf16x8*)(pw + l16 * 72 + kc * 32 + lhi * 8);
#pragma unroll
      for (int nd = 0; nd < 8; ++nd) {
        int d = nd * 16 + l16;
        int g = kc * 4 + lhi;
        bf16x8 bv = *(const bf16x8*)(Vlds + d * 64 + ((g ^ (d & 7)) * 8));
        o[nd] = mfma16(ap, bv, o[nd]);
      }
    }
    __syncthreads();
  }
#pragma unroll
  for (int r = 0; r < 4; ++r) {
    float l = l_part[r];
    l += __shfl_xor(l, 1);
    l += __shfl_xor(l, 2);
    l += __shfl_xor(l, 4);
    l += __shfl_xor(l, 8);
    float inv = 1.0f / l;
    int q = qmin + lhi * 4 + r;
    u16* orow = ao + ((size_t)(b * 1024 + q)) * 4096 + h * 128;
#pragma unroll
    for (int nd = 0; nd < 8; ++nd) orow[nd * 16 + l16] = f2b(o[nd][r] * inv);
  }
}

extern "C" void kernel_launch(void* const* d_in, const int* in_sizes, int n_in,
                              void* d_out, int out_size, void* d_ws, size_t ws_size,
                              hipStream_t stream) {
  const float* x = (const float*)d_in[0];
  const float* wq = (const float*)d_in[2];
  const float* wk = (const float*)d_in[3];
  const float* wv = (const float*)d_in[4];
  const float* wo = (const float*)d_in[5];

  char* ws = (char*)d_ws;
  u16* xb = (u16*)(ws + 0);
  u16* wcat = (u16*)(ws + 33554432);
  u16* qr = (u16*)(ws + 0);
  u16* kr = (u16*)(ws + 33554432);
  u16* vrt = (u16*)(ws + 41943040);
  u16* ao = (u16*)(ws + 50331648);
  u16* wob = (u16*)(ws + 83886080);
  float2* tab = (float2*)(ws + 117440512);
  u16* qkv = (u16*)d_out;

  hipFuncSetAttribute((const void*)k_gemm8<u16>,
                      hipFuncAttributeMaxDynamicSharedMemorySize, 131072);
  hipFuncSetAttribute((const void*)k_gemm8<float>,
                      hipFuncAttributeMaxDynamicSharedMemorySize, 131072);

  k_rope_table<<<256, 256, 0, stream>>>(tab);
  k_cast8<<<8192, 256, 0, stream>>>(x, xb);
  k_tcast3<<<6144, 256, 0, stream>>>(wq, wk, wv, wcat);
  k_tcast<<<4096, 256, 0, stream>>>(wo, wob, 4096, 4096);
  k_gemm8<u16><<<384, 512, 131072, stream>>>(xb, wcat, qkv, 4096, 6144, 4096);
  k_rope8<<<4096, 320, 0, stream>>>(qkv, tab, qr, kr);
  k_vtrans<<<1024, 256, 0, stream>>>(qkv, vrt);
  k_attn<<<1024, 512, 0, stream>>>(qr, kr, vrt, ao);
  k_gemm8<float><<<256, 512, 131072, stream>>>(ao, wob, (float*)d_out, 4096, 4096, 4096);
}

// Round 18
// 533.382 us; speedup vs baseline: 1.0556x; 1.0035x over previous
//
#include <hip/hip_runtime.h>
#include <stdint.h>

typedef unsigned short u16;
typedef __bf16 bf16x8 __attribute__((ext_vector_type(8)));
typedef float f32x4 __attribute__((ext_vector_type(4)));

__device__ __forceinline__ u16 f2b(float x) {
  uint32_t b = __float_as_uint(x);
  b += 0x7fff + ((b >> 16) & 1);
  return (u16)(b >> 16);
}
__device__ __forceinline__ float b2f(u16 u) {
  return __uint_as_float(((uint32_t)u) << 16);
}

#define GLD16(src, dst)                                                                  \
  __builtin_amdgcn_global_load_lds((const __attribute__((address_space(1))) void*)(src),\
                                   (__attribute__((address_space(3))) void*)(dst), 16, 0, 0)

__device__ __forceinline__ f32x4 mfma16(bf16x8 a, bf16x8 b, f32x4 c) {
  return __builtin_amdgcn_mfma_f32_16x16x32_bf16(a, b, c, 0, 0, 0);
}

// ---------------- RoPE cos/sin table
__global__ void k_rope_table(float2* __restrict__ tab) {
  int i = blockIdx.x * 256 + threadIdx.x;  // 65536 = 1024 * 64
  int l = i >> 6, d = i & 63;
  float inv = powf(10000.0f, -(float)(2 * d) / 128.0f);
  float ang = (float)l * inv;
  float s, c;
  sincosf(ang, &s, &c);
  tab[i] = make_float2(c, s);
}

// ---------------- fp32 -> bf16 cast, 8 elems/thread
__global__ void k_cast8(const float* __restrict__ src, u16* __restrict__ dst) {
  size_t i = (size_t)blockIdx.x * 256 + threadIdx.x;
  const float4* s4 = (const float4*)src;
  float4 a = s4[2 * i], b = s4[2 * i + 1];
  union { u16 u[8]; uint4 v; } o;
  o.u[0] = f2b(a.x); o.u[1] = f2b(a.y); o.u[2] = f2b(a.z); o.u[3] = f2b(a.w);
  o.u[4] = f2b(b.x); o.u[5] = f2b(b.y); o.u[6] = f2b(b.z); o.u[7] = f2b(b.w);
  ((uint4*)dst)[i] = o.v;
}

// ---------------- transpose-cast tile body: src fp32 [4096][C] tile -> dst bf16 [C][4096]
__device__ __forceinline__ void tcast_tile(const float* __restrict__ src,
                                           u16* __restrict__ dst, int C, int t) {
  __shared__ u16 tbuf[64][72];
  int tiles_c = C >> 6;
  int tr = t / tiles_c, tc = t % tiles_c;
  int tid = threadIdx.x;
  const int R = 4096;
  {
    int rr = tid >> 4, cv = tid & 15;
#pragma unroll
    for (int it = 0; it < 4; ++it) {
      int row = rr + it * 16;
      float4 v = *(const float4*)(src + (size_t)(tr * 64 + row) * C + tc * 64 + cv * 4);
      tbuf[row][cv * 4 + 0] = f2b(v.x);
      tbuf[row][cv * 4 + 1] = f2b(v.y);
      tbuf[row][cv * 4 + 2] = f2b(v.z);
      tbuf[row][cv * 4 + 3] = f2b(v.w);
    }
  }
  __syncthreads();
  {
    int cc = tid >> 3, g = tid & 7;
#pragma unroll
    for (int it = 0; it < 2; ++it) {
      int c = cc + it * 32;
      union { u16 u[8]; uint4 v; } o;
#pragma unroll
      for (int j = 0; j < 8; ++j) o.u[j] = tbuf[g * 8 + j][c];
      *(uint4*)(dst + (size_t)(tc * 64 + c) * R + tr * 64 + g * 8) = o.v;
    }
  }
}

// single-source transpose-cast (used for wo)
__global__ __launch_bounds__(256) void k_tcast(const float* __restrict__ src,
                                               u16* __restrict__ dst, int R, int C) {
  tcast_tile(src, dst, C, blockIdx.x);
}

// fused wq|wk|wv transpose-cast: blocks [0,4096) wq, [4096,5120) wk, [5120,6144) wv
__global__ __launch_bounds__(256) void k_tcast3(const float* __restrict__ wq,
                                                const float* __restrict__ wk,
                                                const float* __restrict__ wv,
                                                u16* __restrict__ wcat) {
  int bidx = blockIdx.x;
  if (bidx < 4096) {
    tcast_tile(wq, wcat, 4096, bidx);
  } else if (bidx < 5120) {
    tcast_tile(wk, wcat + (size_t)4096 * 4096, 1024, bidx - 4096);
  } else {
    tcast_tile(wv, wcat + (size_t)5120 * 4096, 1024, bidx - 5120);
  }
}

// ---------------- V transpose
__global__ __launch_bounds__(256) void k_vtrans(const u16* __restrict__ qkv,
                                                u16* __restrict__ vrt) {
  __shared__ u16 t[64][72];
  int b = blockIdx.x >> 8;
  int tt = blockIdx.x & 255;
  int tr = tt >> 4, tc = tt & 15;
  int tid = threadIdx.x;
  {
    int rr = tid >> 3, g = tid & 7;
#pragma unroll
    for (int it = 0; it < 2; ++it) {
      int row = rr + it * 32;
      union { u16 u[8]; uint4 v; } o;
      o.v = *(const uint4*)(qkv + (size_t)(b * 1024 + tr * 64 + row) * 6144 + 5120 + tc * 64 + g * 8);
#pragma unroll
      for (int j = 0; j < 8; ++j) t[row][g * 8 + j] = o.u[j];
    }
  }
  __syncthreads();
  {
    int cc = tid >> 3, g = tid & 7;
#pragma unroll
    for (int it = 0; it < 2; ++it) {
      int c = cc + it * 32;
      union { u16 u[8]; uint4 v; } o;
#pragma unroll
      for (int j = 0; j < 8; ++j) o.u[j] = t[g * 8 + j][c];
      *(uint4*)(vrt + (size_t)(b * 1024 + tc * 64 + c) * 1024 + tr * 64 + g * 8) = o.v;
    }
  }
}

// ---------------- RoPE scatter, vectorized 8 pairs/thread (G13)
__global__ __launch_bounds__(320) void k_rope8(const u16* __restrict__ qkv,
                                               const float2* __restrict__ tab,
                                               u16* __restrict__ qr, u16* __restrict__ kr) {
  int row = blockIdx.x;                 // 4096 rows (b*1024+l)
  int j = threadIdx.x * 8;              // pair index: 0..2047 q, 2048..2559 k
  int b = row >> 10, l = row & 1023;
  const float qs = 0.12751586584003446f;  // 128^-0.5 * log2(e)
  bool isq = (j < 2048);
  int jj = isq ? j : (j - 2048);
  int h = jj >> 6, dp = jj & 63;
  const u16* src = qkv + (size_t)row * 6144 + (isq ? 0 : 4096) + h * 128 + 2 * dp;
  uint4 v0 = *(const uint4*)(src);
  uint4 v1 = *(const uint4*)(src + 8);
  const float2* tb = tab + l * 64 + dp;
  float sc = isq ? qs : 1.0f;
  union { u16 u[16]; uint4 v[2]; } o;
  const uint32_t* w = (const uint32_t*)&v0;
#pragma unroll
  for (int i = 0; i < 8; ++i) {
    uint32_t pair = (i < 4) ? w[i] : ((const uint32_t*)&v1)[i - 4];
    float2 cs = tb[i];
    float x1 = b2f((u16)pair), x2 = b2f((u16)(pair >> 16));
    float r1 = (x1 * cs.x - x2 * cs.y) * sc;
    float r2 = (x1 * cs.y + x2 * cs.x) * sc;
    o.u[2 * i] = f2b(r1);
    o.u[2 * i + 1] = f2b(r2);
  }
  u16* dst = isq ? (qr + ((size_t)((b * 32 + h) * 1024 + l)) * 128 + 2 * dp)
                 : (kr + ((size_t)((b * 8 + h) * 1024 + l)) * 128 + 2 * dp);
  *(uint4*)(dst) = o.v[0];
  *(uint4*)(dst + 8) = o.v[1];
}

// ================= 256x256 8-phase bf16 GEMM =================
// R17->R18 (single change): the explicit `s_waitcnt lgkmcnt(0)` after the
// mid-barrier is REMOVED. It forced a full LDS drain before the FIRST MFMA,
// serializing the ~512cyc read window against the ~620cyc MFMA window (39%
// util, matches ledger). The ds_reads are IR-visible, so the compiler emits
// fine-grained counted lgkmcnt before each dependent MFMA (m97 asm evidence)
// -- early MFMAs issue while later reads are in flight. WAR ledger intact:
// each phase's reads are consumed by its own MFMA cluster (counted waits)
// before the trailing barrier, so re-staging 2 phases later is still safe.
#define STAGE2(s0, s1, koff, ldsoff)          \
  GLD16((s0) + (koff), dst0 + (ldsoff));      \
  GLD16((s1) + (koff), dst1 + (ldsoff));

#define LOADB(base, kh)                                                   \
  bfr[0] = *(const bf16x8*)((base) + (kh) * 8192 + 0 * 512);              \
  bfr[1] = *(const bf16x8*)((base) + (kh) * 8192 + 1 * 512);              \
  bfr[2] = *(const bf16x8*)((base) + (kh) * 8192 + 2 * 512);              \
  bfr[3] = *(const bf16x8*)((base) + (kh) * 8192 + 3 * 512);

#define LOADA(base, kh, mh)                                               \
  afr[0] = *(const bf16x8*)((base) + (kh) * 8192 + (mh) * 2048 + 0 * 512);\
  afr[1] = *(const bf16x8*)((base) + (kh) * 8192 + (mh) * 2048 + 1 * 512);\
  afr[2] = *(const bf16x8*)((base) + (kh) * 8192 + (mh) * 2048 + 2 * 512);\
  afr[3] = *(const bf16x8*)((base) + (kh) * 8192 + (mh) * 2048 + 3 * 512);

#define PH(mh)                                                            \
  __builtin_amdgcn_s_barrier();                                           \
  __builtin_amdgcn_s_setprio(1);                                          \
  _Pragma("unroll") for (int mm = 0; mm < 4; ++mm)                        \
    _Pragma("unroll") for (int n_ = 0; n_ < 4; ++n_)                      \
      acc[(mh) * 4 + mm][n_] = mfma16(afr[mm], bfr[n_], acc[(mh) * 4 + mm][n_]); \
  __builtin_amdgcn_s_setprio(0);                                          \
  __builtin_amdgcn_s_barrier();

// phase tail with counted vmcnt AFTER the MFMA cluster
#define PHV(mh, n)                                                        \
  __builtin_amdgcn_s_barrier();                                           \
  __builtin_amdgcn_s_setprio(1);                                          \
  _Pragma("unroll") for (int mm = 0; mm < 4; ++mm)                        \
    _Pragma("unroll") for (int n_ = 0; n_ < 4; ++n_)                      \
      acc[(mh) * 4 + mm][n_] = mfma16(afr[mm], bfr[n_], acc[(mh) * 4 + mm][n_]); \
  __builtin_amdgcn_s_setprio(0);                                          \
  asm volatile("s_waitcnt vmcnt(" #n ")" ::: "memory");                   \
  __builtin_amdgcn_s_barrier();

#define VMC(n) asm volatile("s_waitcnt vmcnt(" #n ")" ::: "memory");

template <typename OutT>
__global__ __launch_bounds__(512, 2) void k_gemm8(const u16* __restrict__ A,
                                                  const u16* __restrict__ Bt,
                                                  OutT* __restrict__ C,
                                                  int M, int N, int K) {
  extern __shared__ u16 lds[];
  const int tid = threadIdx.x;
  const int lane = tid & 63, wid = tid >> 6;
  const int l16 = lane & 15, lhi = lane >> 4;
  const int wm = wid >> 2, wn = wid & 3;

  const int nbn = N >> 8;
  int bid = blockIdx.x;
  const int cpx = gridDim.x >> 3;
  bid = (bid & 7) * cpx + (bid >> 3);  // XCD swizzle (grid % 8 == 0)
  const int bm = (bid / nbn) << 8;
  const int bn = (bid % nbn) << 8;

  const u16* Ag = A + (size_t)bm * K;
  const u16* Bg = Bt + (size_t)bn * K;

  const int swz = (lhi ^ ((l16 >> 1) & 3)) << 3;
  const u16* pA0 = lds + wm * 4096 + l16 * 32 + swz;
  const u16* pA1 = pA0 + 32768;
  const u16* pB0 = lds + 16384 + wn * 2048 + l16 * 32 + swz;
  const u16* pB1 = pB0 + 32768;

  const int r0 = tid >> 2, g0 = tid & 3;
  const int r1 = r0 + 128;
  const size_t so0 = (size_t)r0 * K + ((g0 ^ ((r0 >> 1) & 3)) << 3);
  const size_t so1 = (size_t)r1 * K + ((g0 ^ ((r1 >> 1) & 3)) << 3);
  const u16* sA0 = Ag + so0;
  const u16* sA1 = Ag + so1;
  const u16* sB0 = Bg + so0;
  const u16* sB1 = Bg + so1;
  u16* dst0 = lds + wid * 512;
  u16* dst1 = lds + 4096 + wid * 512;

  f32x4 acc[8][4] = {};
  bf16x8 bfr[4], afr[4];

  STAGE2(sA0, sA1, 0, 0);
  STAGE2(sA0, sA1, 32, 8192);
  STAGE2(sB0, sB1, 0, 16384);
  STAGE2(sB0, sB1, 32, 24576);
  STAGE2(sB0, sB1, 64, 49152);
  STAGE2(sA0, sA1, 64, 32768);
  STAGE2(sB0, sB1, 96, 57344);
  VMC(6)
  __builtin_amdgcn_s_barrier();

  const int nt = K >> 6;
  for (int t = 0; t < nt - 2; t += 2) {
    const int kA1 = (t + 1) * 64 + 32;
    const int k2 = (t + 2) * 64;
    const int k3 = (t + 3) * 64;
    LOADB(pB0, 0)
    LOADA(pA0, 0, 0)
    STAGE2(sA0, sA1, kA1, 40960);
    PH(0)
    LOADA(pA0, 0, 1)
    STAGE2(sB0, sB1, k2, 16384);
    PH(1)
    LOADB(pB0, 1)
    LOADA(pA0, 1, 0)
    STAGE2(sA0, sA1, k2, 0);
    PH(0)
    LOADA(pA0, 1, 1)
    STAGE2(sB0, sB1, k2 + 32, 24576);
    PHV(1, 6)
    LOADB(pB1, 0)
    LOADA(pA1, 0, 0)
    STAGE2(sA0, sA1, k2 + 32, 8192);
    PH(0)
    LOADA(pA1, 0, 1)
    STAGE2(sB0, sB1, k3, 49152);
    PH(1)
    LOADB(pB1, 1)
    LOADA(pA1, 1, 0)
    STAGE2(sA0, sA1, k3, 32768);
    PH(0)
    LOADA(pA1, 1, 1)
    STAGE2(sB0, sB1, k3 + 32, 57344);
    PHV(1, 6)
  }
  {
    const int kA1 = (nt - 1) * 64 + 32;
    LOADB(pB0, 0)
    LOADA(pA0, 0, 0)
    STAGE2(sA0, sA1, kA1, 40960);
    PH(0)
    LOADA(pA0, 0, 1)
    PH(1)
    LOADB(pB0, 1)
    LOADA(pA0, 1, 0)
    PH(0)
    LOADA(pA0, 1, 1)
    PHV(1, 0)
    LOADB(pB1, 0)
    LOADA(pA1, 0, 0)
    PH(0)
    LOADA(pA1, 0, 1)
    PH(1)
    LOADB(pB1, 1)
    LOADA(pA1, 1, 0)
    PH(0)
    LOADA(pA1, 1, 1)
    PH(1)
  }

#pragma unroll
  for (int m = 0; m < 8; ++m) {
    int row = bm + wm * 128 + m * 16 + lhi * 4;
#pragma unroll
    for (int n = 0; n < 4; ++n) {
      int col = bn + wn * 64 + n * 16 + l16;
#pragma unroll
      for (int r = 0; r < 4; ++r) {
        float v = acc[m][n][r];
        size_t idx = (size_t)(row + r) * N + col;
        if constexpr (sizeof(OutT) == 2) C[idx] = f2b(v);
        else C[idx] = v;
      }
    }
  }
}

// ---------------- flash attention (R12-exact, proven)
__global__ __launch_bounds__(512) void k_attn(const u16* __restrict__ qr,
                                              const u16* __restrict__ kr,
                                              const u16* __restrict__ vrt,
                                              u16* __restrict__ ao) {
  __shared__ u16 Klds[8192];
  __shared__ u16 Vlds[8192];
  __shared__ u16 Plds[9216];
  int bid = blockIdx.x;
  int qb = bid & 7, h = (bid >> 3) & 31, b = bid >> 8;
  int kvh = h & 7;
  int lane = threadIdx.x & 63, w = threadIdx.x >> 6;
  int l16 = lane & 15, lhi = lane >> 4;
  int qmin = qb * 128 + w * 16;

  const u16* qbase = qr + ((size_t)((b * 32 + h) * 1024) + qmin + l16) * 128;
  bf16x8 aq[4];
#pragma unroll
  for (int kc = 0; kc < 4; ++kc) aq[kc] = *(const bf16x8*)(qbase + kc * 32 + lhi * 8);

  const u16* Kg = kr + (size_t)(b * 8 + kvh) * (1024 * 128);
  const u16* Vg = vrt + (size_t)(b * 8 + kvh) * (128 * 1024);

  float m_run[4] = {-1e30f, -1e30f, -1e30f, -1e30f};
  float l_part[4] = {0.f, 0.f, 0.f, 0.f};
  f32x4 o[8] = {};

  int nkb = 2 * qb + 2;
  for (int kb = 0; kb < nkb; ++kb) {
    int kv0 = kb * 64;
#pragma unroll
    for (int i = 0; i < 2; ++i) {
      int c = w * 128 + i * 64 + lane;
      int krow = c >> 4, g = c & 15;
      GLD16(Kg + (size_t)(kv0 + krow) * 128 + ((g ^ (krow & 7)) * 8),
            Klds + (w * 128 + i * 64) * 8);
    }
#pragma unroll
    for (int i = 0; i < 2; ++i) {
      int c = w * 128 + i * 64 + lane;
      int d = c >> 3, g = c & 7;
      GLD16(Vg + (size_t)d * 1024 + kv0 + ((g ^ (d & 7)) * 8),
            Vlds + (w * 128 + i * 64) * 8);
    }
    __syncthreads();

    f32x4 s[4] = {};
#pragma unroll
    for (int kc = 0; kc < 4; ++kc) {
#pragma unroll
      for (int n = 0; n < 4; ++n) {
        int kv = n * 16 + l16;
        int g = kc * 4 + lhi;
        bf16x8 bk = *(const bf16x8*)(Klds + kv * 128 + ((g ^ (kv & 7)) * 8));
        s[n] = mfma16(aq[kc], bk, s[n]);
      }
    }
    if (kv0 + 63 > qmin) {
#pragma unroll
      for (int n = 0; n < 4; ++n)
#pragma unroll
        for (int r = 0; r < 4; ++r) {
          int q = qmin + lhi * 4 + r;
          int kv = kv0 + n * 16 + l16;
          if (kv > q) s[n][r] = -1e30f;
        }
    }
    float mx[4];
    bool need = false;
#pragma unroll
    for (int r = 0; r < 4; ++r) {
      float m0 = fmaxf(fmaxf(s[0][r], s[1][r]), fmaxf(s[2][r], s[3][r]));
      m0 = fmaxf(m0, __shfl_xor(m0, 1));
      m0 = fmaxf(m0, __shfl_xor(m0, 2));
      m0 = fmaxf(m0, __shfl_xor(m0, 4));
      m0 = fmaxf(m0, __shfl_xor(m0, 8));
      mx[r] = m0;
      need = need || (m0 > m_run[r] + 11.0f);
    }
    if (__any(need)) {
#pragma unroll
      for (int r = 0; r < 4; ++r) {
        float mn = fmaxf(m_run[r], mx[r]);
        float sf = exp2f(m_run[r] - mn);
        m_run[r] = mn;
        l_part[r] *= sf;
#pragma unroll
        for (int nd = 0; nd < 8; ++nd) o[nd][r] *= sf;
      }
    }
    u16* pw = Plds + w * 1152;
#pragma unroll
    for (int r = 0; r < 4; ++r) {
      float lsum = 0.f;
#pragma unroll
      for (int n = 0; n < 4; ++n) {
        float p = exp2f(s[n][r] - m_run[r]);
        lsum += p;
        pw[(lhi * 4 + r) * 72 + n * 16 + l16] = f2b(p);
      }
      l_part[r] += lsum;
    }
#pragma unroll
    for (int kc = 0; kc < 2; ++kc) {
      bf16x8 ap = *(const bf16x8*)(pw + l16 * 72 + kc * 32 + lhi * 8);
#pragma unroll
      for (int nd = 0; nd < 8; ++nd) {
        int d = nd * 16 + l16;
        int g = kc * 4 + lhi;
        bf16x8 bv = *(const bf16x8*)(Vlds + d * 64 + ((g ^ (d & 7)) * 8));
        o[nd] = mfma16(ap, bv, o[nd]);
      }
    }
    __syncthreads();
  }
#pragma unroll
  for (int r = 0; r < 4; ++r) {
    float l = l_part[r];
    l += __shfl_xor(l, 1);
    l += __shfl_xor(l, 2);
    l += __shfl_xor(l, 4);
    l += __shfl_xor(l, 8);
    float inv = 1.0f / l;
    int q = qmin + lhi * 4 + r;
    u16* orow = ao + ((size_t)(b * 1024 + q)) * 4096 + h * 128;
#pragma unroll
    for (int nd = 0; nd < 8; ++nd) orow[nd * 16 + l16] = f2b(o[nd][r] * inv);
  }
}

extern "C" void kernel_launch(void* const* d_in, const int* in_sizes, int n_in,
                              void* d_out, int out_size, void* d_ws, size_t ws_size,
                              hipStream_t stream) {
  const float* x = (const float*)d_in[0];
  const float* wq = (const float*)d_in[2];
  const float* wk = (const float*)d_in[3];
  const float* wv = (const float*)d_in[4];
  const float* wo = (const float*)d_in[5];

  char* ws = (char*)d_ws;
  u16* xb = (u16*)(ws + 0);
  u16* wcat = (u16*)(ws + 33554432);
  u16* qr = (u16*)(ws + 0);
  u16* kr = (u16*)(ws + 33554432);
  u16* vrt = (u16*)(ws + 41943040);
  u16* ao = (u16*)(ws + 50331648);
  u16* wob = (u16*)(ws + 83886080);
  float2* tab = (float2*)(ws + 117440512);
  u16* qkv = (u16*)d_out;

  hipFuncSetAttribute((const void*)k_gemm8<u16>,
                      hipFuncAttributeMaxDynamicSharedMemorySize, 131072);
  hipFuncSetAttribute((const void*)k_gemm8<float>,
                      hipFuncAttributeMaxDynamicSharedMemorySize, 131072);

  k_rope_table<<<256, 256, 0, stream>>>(tab);
  k_cast8<<<8192, 256, 0, stream>>>(x, xb);
  k_tcast3<<<6144, 256, 0, stream>>>(wq, wk, wv, wcat);
  k_tcast<<<4096, 256, 0, stream>>>(wo, wob, 4096, 4096);
  k_gemm8<u16><<<384, 512, 131072, stream>>>(xb, wcat, qkv, 4096, 6144, 4096);
  k_rope8<<<4096, 320, 0, stream>>>(qkv, tab, qr, kr);
  k_vtrans<<<1024, 256, 0, stream>>>(qkv, vrt);
  k_attn<<<1024, 512, 0, stream>>>(qr, kr, vrt, ao);
  k_gemm8<float><<<256, 512, 131072, stream>>>(ao, wob, (float*)d_out, 4096, 4096, 4096);
}